// Round 5
// baseline (200.027 us; speedup 1.0000x reference)
//
#include <hip/hip_runtime.h>
#include <hip/hip_bf16.h>

#define D_MODEL 1024
#define NHEADS  16
#define HD      64
#define BATCH   2
#define SEQ     2048
#define NTOK    (BATCH * SEQ)   // 4096

typedef __attribute__((ext_vector_type(8))) short bf16x8;
typedef __attribute__((ext_vector_type(4))) float f32x4;

#if __has_builtin(__builtin_amdgcn_exp2f)
#define EXP2F(x) __builtin_amdgcn_exp2f(x)   // raw v_exp_f32
#else
#define EXP2F(x) exp2f(x)
#endif

static __device__ __forceinline__ short f2bf(float f) {
    union { float f; unsigned u; } x; x.f = f;
    unsigned r = (x.u + 0x7fffu + ((x.u >> 16) & 1u)) >> 16;  // RNE
    return (short)r;
}

// pack two fp32 -> bf16 pair (RNE), as one dword
static __device__ __forceinline__ unsigned pk_bf16(float a, float b) {
    __hip_bfloat162 h2 = __float22bfloat162_rn(make_float2(a, b));
    union { __hip_bfloat162 h; unsigned u; } c; c.h = h2;
    return c.u;
}

// async global->LDS, 16B per lane; LDS dest = wave-uniform base + lane*16
static __device__ __forceinline__ void gl_lds16(const short* g, short* l) {
    __builtin_amdgcn_global_load_lds((const __attribute__((address_space(1))) void*)g,
                                     (__attribute__((address_space(3))) void*)l,
                                     16, 0, 0);
}

// ---------------------------------------------------------------------------
// Fused prep: cast x -> bf16 (blocks 0..4095), transpose+cast Wqkv with
// softmax scale folded into Q-columns (blocks 4096..7167), transpose+cast Wo
// (blocks 7168..8191). One launch instead of three.
// ---------------------------------------------------------------------------
__global__ __launch_bounds__(256) void prep_kernel(const float* __restrict__ x,
                                                   short* __restrict__ x_bf,
                                                   const float* __restrict__ Wqkv,
                                                   short* __restrict__ WqkvT,
                                                   const float* __restrict__ Wo,
                                                   short* __restrict__ WoT,
                                                   float cexp) {
    int bid = blockIdx.x;
    int tid = threadIdx.x;

    if (bid < 4096) {
        int i = bid * 256 + tid;
        float4 v = ((const float4*)x)[i];
        short4 o;
        o.x = f2bf(v.x); o.y = f2bf(v.y); o.z = f2bf(v.z); o.w = f2bf(v.w);
        ((short4*)x_bf)[i] = o;
        return;
    }

    __shared__ float tile[32][33];
    const float* in; short* out; int R, C, slimit; float sc; int bx, by;
    if (bid < 4096 + 3072) {
        int idx = bid - 4096;
        in = Wqkv; out = WqkvT; R = D_MODEL; C = 3 * D_MODEL;
        slimit = D_MODEL; sc = cexp;
        bx = idx % 96; by = idx / 96;
    } else {
        int idx = bid - 7168;
        in = Wo; out = WoT; R = D_MODEL; C = D_MODEL;
        slimit = 0; sc = 1.0f;
        bx = idx % 32; by = idx / 32;
    }
    int bc = bx * 32, br = by * 32;
    int tx = tid & 31, ty = tid >> 5;   // 32 x 8
    #pragma unroll
    for (int i = 0; i < 32; i += 8)
        tile[ty + i][tx] = in[(long)(br + ty + i) * C + bc + tx];
    __syncthreads();
    #pragma unroll
    for (int i = 0; i < 32; i += 8) {
        int orow = bc + ty + i;
        float v = tile[tx][ty + i];
        if (orow < slimit) v *= sc;
        out[(long)orow * R + br + tx] = f2bf(v);
    }
}

// ---------------------------------------------------------------------------
// Output-proj GEMM: 128x64 tiles (512 blocks = 2/CU). Wave w: rows
// [w*32, w*32+32), all 64 cols -> 2x4 frags.
// ---------------------------------------------------------------------------
__global__ __launch_bounds__(256) void gemm_out(const short* __restrict__ A,
                                                const short* __restrict__ BT,
                                                float* __restrict__ C,
                                                int M, int N, int K) {
    __shared__ short As[128 * 32];
    __shared__ short Bs[64 * 32];

    int tid  = threadIdx.x;
    int lane = tid & 63;
    int w    = tid >> 6;
    int quad = lane >> 4;
    int l16  = lane & 15;

    int m_blk = blockIdx.y * 128, n_blk = blockIdx.x * 64;

    const short* Ag = A  + (long)(m_blk + w * 32 + (lane >> 2)) * K + (lane & 3) * 8;
    const short* Bg = BT + (long)(n_blk + w * 16 + (lane >> 2)) * K + (lane & 3) * 8;
    short* AsW = &As[(w * 32) * 32];
    short* BsW = &Bs[(w * 16) * 32];

    f32x4 acc[2][4] = {};

    for (int k0 = 0; k0 < K; k0 += 32) {
        __syncthreads();
        gl_lds16(Ag + k0,          AsW);
        gl_lds16(Ag + 16 * K + k0, AsW + 16 * 32);
        gl_lds16(Bg + k0,          BsW);
        __syncthreads();

        bf16x8 a[2], b[4];
        #pragma unroll
        for (int i = 0; i < 2; i++)
            a[i] = *(const bf16x8*)&As[(w * 32 + i * 16 + l16) * 32 + quad * 8];
        #pragma unroll
        for (int j = 0; j < 4; j++)
            b[j] = *(const bf16x8*)&Bs[(j * 16 + l16) * 32 + quad * 8];
        #pragma unroll
        for (int i = 0; i < 2; i++)
            #pragma unroll
            for (int j = 0; j < 4; j++)
                acc[i][j] = __builtin_amdgcn_mfma_f32_16x16x32_bf16(a[i], b[j], acc[i][j], 0, 0, 0);
    }

    #pragma unroll
    for (int i = 0; i < 2; i++)
        #pragma unroll
        for (int j = 0; j < 4; j++)
            #pragma unroll
            for (int r = 0; r < 4; r++) {
                int row = m_blk + w * 32 + i * 16 + quad * 4 + r;
                int col = n_blk + j * 16 + l16;
                C[(long)row * N + col] = acc[i][j][r];
            }
}

// ---------------------------------------------------------------------------
// QKV GEMM: m97 structure, bf16 out split into Qb/Kb/Vb by n-range.
// ---------------------------------------------------------------------------
__global__ __launch_bounds__(256) void gemm_qkv(const short* __restrict__ A,
                                                const short* __restrict__ BT,
                                                short* __restrict__ Qb,
                                                short* __restrict__ Kb,
                                                short* __restrict__ Vb) {
    const int K = 1024;
    __shared__ short As[128 * 32];
    __shared__ short Bs[128 * 32];

    int tid  = threadIdx.x;
    int lane = tid & 63;
    int w    = tid >> 6;
    int quad = lane >> 4;
    int l16  = lane & 15;

    int m_blk = blockIdx.y * 128, n_blk = blockIdx.x * 128;
    int mh = (w >> 1) * 64, nh = (w & 1) * 64;

    int sel = blockIdx.x >> 3;                 // 0:Q 1:K 2:V
    short* outb = (sel == 0) ? Qb : (sel == 1) ? Kb : Vb;
    int ncol0 = n_blk - sel * 1024;

    const short* Ag = A  + (long)(m_blk + w * 32 + (lane >> 2)) * K + (lane & 3) * 8;
    const short* Bg = BT + (long)(n_blk + w * 32 + (lane >> 2)) * K + (lane & 3) * 8;
    short* AsW = &As[(w * 32) * 32];
    short* BsW = &Bs[(w * 32) * 32];

    f32x4 acc[4][4] = {};

    for (int k0 = 0; k0 < K; k0 += 32) {
        __syncthreads();
        gl_lds16(Ag + k0,          AsW);
        gl_lds16(Ag + 16 * K + k0, AsW + 16 * 32);
        gl_lds16(Bg + k0,          BsW);
        gl_lds16(Bg + 16 * K + k0, BsW + 16 * 32);
        __syncthreads();

        bf16x8 a[4], b[4];
        #pragma unroll
        for (int i = 0; i < 4; i++)
            a[i] = *(const bf16x8*)&As[(mh + i * 16 + l16) * 32 + quad * 8];
        #pragma unroll
        for (int j = 0; j < 4; j++)
            b[j] = *(const bf16x8*)&Bs[(nh + j * 16 + l16) * 32 + quad * 8];
        #pragma unroll
        for (int i = 0; i < 4; i++)
            #pragma unroll
            for (int j = 0; j < 4; j++)
                acc[i][j] = __builtin_amdgcn_mfma_f32_16x16x32_bf16(a[i], b[j], acc[i][j], 0, 0, 0);
    }

    #pragma unroll
    for (int i = 0; i < 4; i++)
        #pragma unroll
        for (int j = 0; j < 4; j++)
            #pragma unroll
            for (int r = 0; r < 4; r++) {
                int row = m_blk + mh + i * 16 + quad * 4 + r;
                int col = ncol0 + nh + j * 16 + l16;
                outb[(long)row * 1024 + col] = f2bf(acc[i][j][r]);
            }
}

// ---------------------------------------------------------------------------
// Repack K and V into MFMA-B-fragment-ready tiles (per bh, per 64-key tile):
//   Kt2 chunks u: element = K[(u>>2)*32+((u>>1)&1)*16+l16][(u&1)*32+quad*8+j]
//   Vt2 chunks (c,j): element = V[key(s)][j*16+l16], s=c*32+quad*8+jj,
//     key(s) = (s>>2)+((s&3)<<4)   (matches flash's b64 P-pack order)
// ---------------------------------------------------------------------------
__global__ __launch_bounds__(256) void repack_kv(const short* __restrict__ Kb,
                                                 const short* __restrict__ Vb,
                                                 short* __restrict__ Kt2,
                                                 short* __restrict__ Vt2) {
    __shared__ short Kl[64][72];
    __shared__ short Vl[64][72];
    int t = blockIdx.x, bh = blockIdx.y;
    int b = bh >> 4, h = bh & 15;
    int tid = threadIdx.x;

    int r  = tid >> 2;
    int cc = (tid & 3) * 16;
    const short* ks = Kb + ((long)b * SEQ + t * 64 + r) * 1024 + h * 64 + cc;
    const short* vs = Vb + ((long)b * SEQ + t * 64 + r) * 1024 + h * 64 + cc;
    *(bf16x8*)&Kl[r][cc]     = *(const bf16x8*)(ks);
    *(bf16x8*)&Kl[r][cc + 8] = *(const bf16x8*)(ks + 8);
    *(bf16x8*)&Vl[r][cc]     = *(const bf16x8*)(vs);
    *(bf16x8*)&Vl[r][cc + 8] = *(const bf16x8*)(vs + 8);
    __syncthreads();

    long obase = (long)bh * (SEQ * 64) + t * 4096;

    #pragma unroll
    for (int ch = 0; ch < 2; ch++) {
        int o = tid * 16 + ch * 8;
        int u = o >> 9, qd = (o >> 7) & 3, l = (o >> 3) & 15;
        int row = (u >> 2) * 32 + ((u >> 1) & 1) * 16 + l;
        int col = (u & 1) * 32 + qd * 8;
        *(bf16x8*)(Kt2 + obase + o) = *(const bf16x8*)&Kl[row][col];
    }
    #pragma unroll
    for (int ch = 0; ch < 2; ch++) {
        int o = tid * 16 + ch * 8;
        int c = o >> 11, j = (o >> 9) & 3, qd = (o >> 7) & 3, l = (o >> 3) & 15;
        int hd = j * 16 + l;
        bf16x8 ov;
        #pragma unroll
        for (int jj = 0; jj < 8; jj++) {
            int s = c * 32 + qd * 8 + jj;
            int key = (s >> 2) + ((s & 3) << 4);
            ov[jj] = Vl[key][hd];
        }
        *(bf16x8*)(Vt2 + obase + o) = ov;
    }
}

// ---------------------------------------------------------------------------
// Flash attention, round-5: R0 geometry + R4 locality.
//   Block = 64 q-rows: 2 q-tiles (qsel=w&1) x 2-way key split (ksel=w>>1).
//   Wave pairs (w0,w1) / (w2,w3) issue IDENTICAL kf/vf loads (intra-block
//   sharing, R4's lesson) while grid = 1024 blocks = 4 blocks/CU = 16
//   waves/CU — the register-cap maximum (128 unified regs/thread).
//   R4 proved 512 blocks (2/CU, 8 waves) is TLP-starved: FETCH fixed at
//   13.9 MB but dur flat at 62 µs, Occupancy 17.7%.
//   T1 bijective XCD-chunk swizzle (1024 % 8 == 0): 128 blocks = 4 bh
//   = 2 MB K/V per XCD's L2 (R4-verified, FETCH 70 -> 13.9 MB).
//   Loop body + 2-way merge byte-identical to R0's verified code
//   (64 arch + 64 acc regs, no spill; R3 proved any extra live frag spills).
//   setprio(1) around MFMA clusters (barrier-free desynced waves, m191).
// ---------------------------------------------------------------------------
__global__ __launch_bounds__(256, 4) void flash_attn(const short* __restrict__ Qb,
                                                     const short* __restrict__ Kt2,
                                                     const short* __restrict__ Vt2,
                                                     short* __restrict__ y) {
    int tid  = threadIdx.x;
    int lane = tid & 63;
    int w    = tid >> 6;
    int quad = lane >> 4;
    int l16  = lane & 15;
    int qsel = w & 1;
    int ksel = w >> 1;

    // T1: bijective XCD-chunked swizzle (1024 % 8 == 0)
    int bid0 = blockIdx.x;
    int nid  = (bid0 & 7) * 128 + (bid0 >> 3);
    int bh   = nid >> 5;        // 4 consecutive bh per XCD
    int b    = bh >> 4;
    int h    = bh & 15;
    int qw   = (nid & 31) * 64 + qsel * 32;

    __shared__ union {
        short Ps[4][32 * 72];   // wave-private P tiles (18432 B)
        float Mg[2][64][41];    // merge buffers (20992 B), used after loop
    } sh;
    short* PsW = &sh.Ps[w][0];

    const short* Qrow = Qb + ((long)b * SEQ + qw + l16) * 1024 + h * 64;
    bf16x8 aQ[2][2];
    #pragma unroll
    for (int m = 0; m < 2; m++)
        #pragma unroll
        for (int c = 0; c < 2; c++)
            aQ[m][c] = *(const bf16x8*)(Qrow + (long)(m * 16) * 1024 + c * 32 + quad * 8);

    const short* Ktb = Kt2 + (long)bh * (SEQ * 64) + (long)ksel * 16 * 4096;
    const short* Vtb = Vt2 + (long)bh * (SEQ * 64) + (long)ksel * 16 * 4096;

    f32x4 O[2][4] = {};
    f32x4 Lacc[2] = {};
    bf16x8 ones;
    #pragma unroll
    for (int i = 0; i < 8; i++) ones[i] = (short)0x3F80;   // bf16 1.0

    for (int t = 0; t < 16; t++) {
        const short* Kt = Ktb + t * 4096;
        const short* Vt = Vtb + t * 4096;

        // K fragment loads (1KB dwordx4; shared by wave pair -> L1/L2-hot)
        bf16x8 kf[8];
        #pragma unroll
        for (int u = 0; u < 8; u++) kf[u] = *(const bf16x8*)(Kt + u * 512 + lane * 8);

        // S = Q K^T: 2 m-frags x 4 key-cols, 2 chained d-chunks each
        __builtin_amdgcn_s_setprio(1);
        f32x4 z[2][4];
        #pragma unroll
        for (int m = 0; m < 2; m++)
            #pragma unroll
            for (int kc = 0; kc < 4; kc++) {
                f32x4 zz = {};
                zz = __builtin_amdgcn_mfma_f32_16x16x32_bf16(aQ[m][0], kf[2 * kc],     zz, 0, 0, 0);
                z[m][kc] = __builtin_amdgcn_mfma_f32_16x16x32_bf16(aQ[m][1], kf[2 * kc + 1], zz, 0, 0, 0);
            }
        __builtin_amdgcn_s_setprio(0);

        // V fragment loads — issued now, consumed after exp/pack (latency hidden)
        bf16x8 vf[8];
        #pragma unroll
        for (int u = 0; u < 8; u++) vf[u] = *(const bf16x8*)(Vt + u * 512 + lane * 8);

        // p = exp2(z) (raw v_exp_f32); packed bf16 cvt; one b64 write per (m,r)
        #pragma unroll
        for (int m = 0; m < 2; m++)
            #pragma unroll
            for (int r = 0; r < 4; r++) {
                unsigned d0 = pk_bf16(EXP2F(z[m][0][r]), EXP2F(z[m][1][r]));
                unsigned d1 = pk_bf16(EXP2F(z[m][2][r]), EXP2F(z[m][3][r]));
                unsigned long long dd = ((unsigned long long)d1 << 32) | d0;
                *(unsigned long long*)((unsigned*)PsW + (m * 16 + quad * 4 + r) * 36 + 2 * l16) = dd;
            }

        // PV + row-sum (ones-column MFMA); bV shared across both m-frags
        __builtin_amdgcn_s_setprio(1);
        #pragma unroll
        for (int c = 0; c < 2; c++) {
            bf16x8 aP0 = *(const bf16x8*)(PsW + (l16) * 72      + c * 32 + quad * 8);
            bf16x8 aP1 = *(const bf16x8*)(PsW + (16 + l16) * 72 + c * 32 + quad * 8);
            Lacc[0] = __builtin_amdgcn_mfma_f32_16x16x32_bf16(aP0, ones, Lacc[0], 0, 0, 0);
            Lacc[1] = __builtin_amdgcn_mfma_f32_16x16x32_bf16(aP1, ones, Lacc[1], 0, 0, 0);
            #pragma unroll
            for (int j = 0; j < 4; j++) {
                O[0][j] = __builtin_amdgcn_mfma_f32_16x16x32_bf16(aP0, vf[c * 4 + j], O[0][j], 0, 0, 0);
                O[1][j] = __builtin_amdgcn_mfma_f32_16x16x32_bf16(aP1, vf[c * 4 + j], O[1][j], 0, 0, 0);
            }
        }
        __builtin_amdgcn_s_setprio(0);
    }

    // additive merge of key-split partners (w, w+2) — Ps is dead, reuse as Mg
    __syncthreads();
    if (ksel) {
        float* mg = &sh.Mg[qsel][lane][0];
        #pragma unroll
        for (int m = 0; m < 2; m++)
            #pragma unroll
            for (int j = 0; j < 4; j++)
                #pragma unroll
                for (int r = 0; r < 4; r++)
                    mg[m * 16 + j * 4 + r] = O[m][j][r];
        #pragma unroll
        for (int m = 0; m < 2; m++)
            #pragma unroll
            for (int r = 0; r < 4; r++)
                mg[32 + m * 4 + r] = Lacc[m][r];
    }
    __syncthreads();
    if (!ksel) {
        const float* mg = &sh.Mg[qsel][lane][0];
        #pragma unroll
        for (int m = 0; m < 2; m++)
            #pragma unroll
            for (int j = 0; j < 4; j++)
                #pragma unroll
                for (int r = 0; r < 4; r++)
                    O[m][j][r] += mg[m * 16 + j * 4 + r];
        #pragma unroll
        for (int m = 0; m < 2; m++)
            #pragma unroll
            for (int r = 0; r < 4; r++)
                Lacc[m][r] += mg[32 + m * 4 + r];

        #pragma unroll
        for (int m = 0; m < 2; m++) {
            f32x4 rl;
            #pragma unroll
            for (int r = 0; r < 4; r++) rl[r] = 1.0f / Lacc[m][r];
            #pragma unroll
            for (int j = 0; j < 4; j++)
                #pragma unroll
                for (int r = 0; r < 4; r++) {
                    int row = qw + m * 16 + quad * 4 + r;
                    y[((long)b * SEQ + row) * D_MODEL + h * HD + j * 16 + l16] =
                        f2bf(O[m][j][r] * rl[r]);
                }
        }
    }
}

// ---------------------------------------------------------------------------
// Workspace (48 MB): Qb@0, Kb@8M (yb aliases after repack), Vb@16M,
// Kt2@24M, Vt2@32M, WqkvT@40M, WoT@46M. x_bf scratched in d_out.
// ---------------------------------------------------------------------------
extern "C" void kernel_launch(void* const* d_in, const int* in_sizes, int n_in,
                              void* d_out, int out_size, void* d_ws, size_t ws_size,
                              hipStream_t stream) {
    const float* x    = (const float*)d_in[0];
    const float* Wqkv = (const float*)d_in[1];
    const float* Wo   = (const float*)d_in[2];

    char* ws = (char*)d_ws;
    short* Qb    = (short*)(ws);
    short* Kb    = (short*)(ws + 8388608);
    short* Vb    = (short*)(ws + 16777216);
    short* Kt2   = (short*)(ws + 25165824);
    short* Vt2   = (short*)(ws + 33554432);
    short* WqkvT = (short*)(ws + 41943040);
    short* WoT   = (short*)(ws + 48234496);
    short* x_bf  = (short*)d_out;            // scratch in d_out (16 MB fp32)
    short* yb    = Kb;                       // Kb dead after repack_kv

    const float cexp = 0.125f * 1.4426950408889634f;  // 1/sqrt(64) * log2(e)

    prep_kernel<<<8192, 256, 0, stream>>>(x, x_bf, Wqkv, WqkvT, Wo, WoT, cexp);

    gemm_qkv<<<dim3(3 * D_MODEL / 128, NTOK / 128), 256, 0, stream>>>(
        x_bf, WqkvT, Qb, Kb, Vb);

    repack_kv<<<dim3(SEQ / 64, BATCH * NHEADS), 256, 0, stream>>>(Kb, Vb, Kt2, Vt2);

    flash_attn<<<1024, 256, 0, stream>>>(Qb, Kt2, Vt2, yb);

    gemm_out<<<dim3(D_MODEL / 64, NTOK / 128), 256, 0, stream>>>(
        yb, WoT, (float*)d_out, NTOK, D_MODEL, D_MODEL);
}

// Round 6
// 188.142 us; speedup vs baseline: 1.0632x; 1.0632x over previous
//
#include <hip/hip_runtime.h>
#include <hip/hip_bf16.h>

#define D_MODEL 1024
#define NHEADS  16
#define HD      64
#define BATCH   2
#define SEQ     2048
#define NTOK    (BATCH * SEQ)   // 4096

typedef __attribute__((ext_vector_type(8))) short bf16x8;
typedef __attribute__((ext_vector_type(4))) float f32x4;

#if __has_builtin(__builtin_amdgcn_exp2f)
#define EXP2F(x) __builtin_amdgcn_exp2f(x)   // raw v_exp_f32
#else
#define EXP2F(x) exp2f(x)
#endif

static __device__ __forceinline__ short f2bf(float f) {
    union { float f; unsigned u; } x; x.f = f;
    unsigned r = (x.u + 0x7fffu + ((x.u >> 16) & 1u)) >> 16;  // RNE
    return (short)r;
}

// pack two fp32 -> bf16 pair (RNE), as one dword
static __device__ __forceinline__ unsigned pk_bf16(float a, float b) {
    __hip_bfloat162 h2 = __float22bfloat162_rn(make_float2(a, b));
    union { __hip_bfloat162 h; unsigned u; } c; c.h = h2;
    return c.u;
}

// async global->LDS, 16B per lane; LDS dest = wave-uniform base + lane*16
static __device__ __forceinline__ void gl_lds16(const short* g, short* l) {
    __builtin_amdgcn_global_load_lds((const __attribute__((address_space(1))) void*)g,
                                     (__attribute__((address_space(3))) void*)l,
                                     16, 0, 0);
}

// ---------------------------------------------------------------------------
// Fused prep: cast x -> bf16 (blocks 0..4095), transpose+cast Wqkv with
// softmax scale folded into Q-columns (blocks 4096..7167), transpose+cast Wo
// (blocks 7168..8191). One launch instead of three.
// ---------------------------------------------------------------------------
__global__ __launch_bounds__(256) void prep_kernel(const float* __restrict__ x,
                                                   short* __restrict__ x_bf,
                                                   const float* __restrict__ Wqkv,
                                                   short* __restrict__ WqkvT,
                                                   const float* __restrict__ Wo,
                                                   short* __restrict__ WoT,
                                                   float cexp) {
    int bid = blockIdx.x;
    int tid = threadIdx.x;

    if (bid < 4096) {
        int i = bid * 256 + tid;
        float4 v = ((const float4*)x)[i];
        short4 o;
        o.x = f2bf(v.x); o.y = f2bf(v.y); o.z = f2bf(v.z); o.w = f2bf(v.w);
        ((short4*)x_bf)[i] = o;
        return;
    }

    __shared__ float tile[32][33];
    const float* in; short* out; int R, C, slimit; float sc; int bx, by;
    if (bid < 4096 + 3072) {
        int idx = bid - 4096;
        in = Wqkv; out = WqkvT; R = D_MODEL; C = 3 * D_MODEL;
        slimit = D_MODEL; sc = cexp;
        bx = idx % 96; by = idx / 96;
    } else {
        int idx = bid - 7168;
        in = Wo; out = WoT; R = D_MODEL; C = D_MODEL;
        slimit = 0; sc = 1.0f;
        bx = idx % 32; by = idx / 32;
    }
    int bc = bx * 32, br = by * 32;
    int tx = tid & 31, ty = tid >> 5;   // 32 x 8
    #pragma unroll
    for (int i = 0; i < 32; i += 8)
        tile[ty + i][tx] = in[(long)(br + ty + i) * C + bc + tx];
    __syncthreads();
    #pragma unroll
    for (int i = 0; i < 32; i += 8) {
        int orow = bc + ty + i;
        float v = tile[tx][ty + i];
        if (orow < slimit) v *= sc;
        out[(long)orow * R + br + tx] = f2bf(v);
    }
}

// ---------------------------------------------------------------------------
// Output-proj GEMM: 128x64 tiles (512 blocks = 2/CU). Wave w: rows
// [w*32, w*32+32), all 64 cols -> 2x4 frags.
// ---------------------------------------------------------------------------
__global__ __launch_bounds__(256) void gemm_out(const short* __restrict__ A,
                                                const short* __restrict__ BT,
                                                float* __restrict__ C,
                                                int M, int N, int K) {
    __shared__ short As[128 * 32];
    __shared__ short Bs[64 * 32];

    int tid  = threadIdx.x;
    int lane = tid & 63;
    int w    = tid >> 6;
    int quad = lane >> 4;
    int l16  = lane & 15;

    int m_blk = blockIdx.y * 128, n_blk = blockIdx.x * 64;

    const short* Ag = A  + (long)(m_blk + w * 32 + (lane >> 2)) * K + (lane & 3) * 8;
    const short* Bg = BT + (long)(n_blk + w * 16 + (lane >> 2)) * K + (lane & 3) * 8;
    short* AsW = &As[(w * 32) * 32];
    short* BsW = &Bs[(w * 16) * 32];

    f32x4 acc[2][4] = {};

    for (int k0 = 0; k0 < K; k0 += 32) {
        __syncthreads();
        gl_lds16(Ag + k0,          AsW);
        gl_lds16(Ag + 16 * K + k0, AsW + 16 * 32);
        gl_lds16(Bg + k0,          BsW);
        __syncthreads();

        bf16x8 a[2], b[4];
        #pragma unroll
        for (int i = 0; i < 2; i++)
            a[i] = *(const bf16x8*)&As[(w * 32 + i * 16 + l16) * 32 + quad * 8];
        #pragma unroll
        for (int j = 0; j < 4; j++)
            b[j] = *(const bf16x8*)&Bs[(j * 16 + l16) * 32 + quad * 8];
        #pragma unroll
        for (int i = 0; i < 2; i++)
            #pragma unroll
            for (int j = 0; j < 4; j++)
                acc[i][j] = __builtin_amdgcn_mfma_f32_16x16x32_bf16(a[i], b[j], acc[i][j], 0, 0, 0);
    }

    #pragma unroll
    for (int i = 0; i < 2; i++)
        #pragma unroll
        for (int j = 0; j < 4; j++)
            #pragma unroll
            for (int r = 0; r < 4; r++) {
                int row = m_blk + w * 32 + i * 16 + quad * 4 + r;
                int col = n_blk + j * 16 + l16;
                C[(long)row * N + col] = acc[i][j][r];
            }
}

// ---------------------------------------------------------------------------
// QKV GEMM with FUSED repack epilogue. m97 K-loop unchanged. Epilogue:
// each wave's 64x64 acc subtile is staged (f2bf) into a wave-private LDS
// tile (union with the dead As/Bs; one barrier guards the aliasing), then:
//   sel 0 (Q): written row-major to Qb as 8x b128 stores/lane (was 64 scalar)
//   sel 1 (K): one complete Kt2 fragment tile; repack's chunk formula:
//        o=lane*64+ch*8; u=o>>9 qd=(o>>7)&3 l=(o>>3)&15
//        elem = T[(u>>2)*32+((u>>1)&1)*16+l][(u&1)*32+qd*8+j]
//   sel 2 (V): one complete Vt2 tile; gather formula:
//        c=o>>11 j2=(o>>9)&3 qd=(o>>7)&3 l=(o>>3)&15; hd=j2*16+l
//        ov[jj]=T[key][hd], s=c*32+qd*8+jj, key=(s>>2)+((s&3)<<4)
// Eliminates the repack_kv kernel: no Kb/Vb HBM write + re-read (32 MB),
// values bit-identical (f2bf applied at the same point as before).
// Wave-private LDS write->read without barrier = same idiom flash uses
// for its P tile (per-wave DS ops are ordered; compiler emits lgkmcnt).
// ---------------------------------------------------------------------------
__global__ __launch_bounds__(256) void gemm_qkv(const short* __restrict__ A,
                                                const short* __restrict__ BT,
                                                short* __restrict__ Qb,
                                                short* __restrict__ Kt2,
                                                short* __restrict__ Vt2) {
    const int K = 1024;
    __shared__ union {
        struct { short As[128 * 32]; short Bs[128 * 32]; } g;
        short Tl[4][64][72];            // wave-private 64x64 epilogue tiles
    } sh;

    int tid  = threadIdx.x;
    int lane = tid & 63;
    int w    = tid >> 6;
    int quad = lane >> 4;
    int l16  = lane & 15;

    int m_blk = blockIdx.y * 128, n_blk = blockIdx.x * 128;
    int mh = (w >> 1) * 64, nh = (w & 1) * 64;

    int sel = blockIdx.x >> 3;                 // 0:Q 1:K 2:V (uniform per block)
    int ncol0 = n_blk - sel * 1024;

    const short* Ag = A  + (long)(m_blk + w * 32 + (lane >> 2)) * K + (lane & 3) * 8;
    const short* Bg = BT + (long)(n_blk + w * 32 + (lane >> 2)) * K + (lane & 3) * 8;
    short* AsW = &sh.g.As[(w * 32) * 32];
    short* BsW = &sh.g.Bs[(w * 32) * 32];

    f32x4 acc[4][4] = {};

    for (int k0 = 0; k0 < K; k0 += 32) {
        __syncthreads();
        gl_lds16(Ag + k0,          AsW);
        gl_lds16(Ag + 16 * K + k0, AsW + 16 * 32);
        gl_lds16(Bg + k0,          BsW);
        gl_lds16(Bg + 16 * K + k0, BsW + 16 * 32);
        __syncthreads();

        bf16x8 a[4], b[4];
        #pragma unroll
        for (int i = 0; i < 4; i++)
            a[i] = *(const bf16x8*)&sh.g.As[(mh + i * 16 + l16) * 32 + quad * 8];
        #pragma unroll
        for (int j = 0; j < 4; j++)
            b[j] = *(const bf16x8*)&sh.g.Bs[(nh + j * 16 + l16) * 32 + quad * 8];
        #pragma unroll
        for (int i = 0; i < 4; i++)
            #pragma unroll
            for (int j = 0; j < 4; j++)
                acc[i][j] = __builtin_amdgcn_mfma_f32_16x16x32_bf16(a[i], b[j], acc[i][j], 0, 0, 0);
    }

    // all waves done with As/Bs before the union is reused
    __syncthreads();

    // stage this wave's 64x64 bf16 tile into its private LDS buffer
    #pragma unroll
    for (int i = 0; i < 4; i++)
        #pragma unroll
        for (int j = 0; j < 4; j++)
            #pragma unroll
            for (int r = 0; r < 4; r++)
                sh.Tl[w][i * 16 + quad * 4 + r][j * 16 + l16] = f2bf(acc[i][j][r]);

    int R0q = m_blk + mh;                      // global token-row base of subtile
    if (sel == 0) {
        long qbase = (long)R0q * 1024 + (ncol0 + nh);
        #pragma unroll
        for (int ch = 0; ch < 8; ch++) {
            int row  = ch * 8 + (lane >> 3);
            int col0 = (lane & 7) * 8;
            *(bf16x8*)(Qb + qbase + (long)row * 1024 + col0) =
                *(const bf16x8*)&sh.Tl[w][row][col0];
        }
    } else {
        int b2 = R0q >> 11;                    // batch
        int t  = (R0q & 2047) >> 6;            // 64-key tile within sequence
        int h  = (ncol0 + nh) >> 6;            // head
        long obase = (long)(b2 * 16 + h) * (SEQ * 64) + (long)t * 4096;
        short* outT = (sel == 1) ? Kt2 : Vt2;
        if (sel == 1) {
            #pragma unroll
            for (int ch = 0; ch < 8; ch++) {
                int o = lane * 64 + ch * 8;
                int u = o >> 9, qd = (o >> 7) & 3, l = (o >> 3) & 15;
                int row = (u >> 2) * 32 + ((u >> 1) & 1) * 16 + l;
                int col = (u & 1) * 32 + qd * 8;
                *(bf16x8*)(outT + obase + o) = *(const bf16x8*)&sh.Tl[w][row][col];
            }
        } else {
            #pragma unroll
            for (int ch = 0; ch < 8; ch++) {
                int o = lane * 64 + ch * 8;
                int c = o >> 11, j2 = (o >> 9) & 3, qd = (o >> 7) & 3, l = (o >> 3) & 15;
                int hd = j2 * 16 + l;
                bf16x8 ov;
                #pragma unroll
                for (int jj = 0; jj < 8; jj++) {
                    int s = c * 32 + qd * 8 + jj;
                    int key = (s >> 2) + ((s & 3) << 4);
                    ov[jj] = sh.Tl[w][key][hd];
                }
                *(bf16x8*)(outT + obase + o) = ov;
            }
        }
    }
}

// ---------------------------------------------------------------------------
// Flash attention: byte-exact round-0 version (best measured: 57.2 us).
// Fragment-direct, 32 q/wave, K-split x2; grid (SEQ/64, BH) = 1024 blocks.
// R1-R5 established: occupancy is register-capped at 4 waves/SIMD (64 arch
// + 64 acc regs; tighter launch_bounds or extra live frags spill), and dur
// is invariant (57-62 us) to FETCH 14-71 MB / occupancy 17-33% -> the chain
// is issue-bound, not load-latency-bound. Swizzle+setprio (R5) cost ~3 us;
// reverted. Further gains require the 8-warp co-designed structure.
// ---------------------------------------------------------------------------
__global__ __launch_bounds__(256, 4) void flash_attn(const short* __restrict__ Qb,
                                                     const short* __restrict__ Kt2,
                                                     const short* __restrict__ Vt2,
                                                     short* __restrict__ y) {
    int tid  = threadIdx.x;
    int lane = tid & 63;
    int w    = tid >> 6;
    int quad = lane >> 4;
    int l16  = lane & 15;
    int qsel = w & 1;
    int ksel = w >> 1;

    int bh = blockIdx.y;
    int b  = bh >> 4;
    int h  = bh & 15;
    int qw = blockIdx.x * 64 + qsel * 32;

    __shared__ union {
        short Ps[4][32 * 72];   // wave-private P tiles (18432 B)
        float Mg[2][64][41];    // merge buffers (20992 B), used after loop
    } sh;
    short* PsW = &sh.Ps[w][0];

    const short* Qrow = Qb + ((long)b * SEQ + qw + l16) * 1024 + h * 64;
    bf16x8 aQ[2][2];
    #pragma unroll
    for (int m = 0; m < 2; m++)
        #pragma unroll
        for (int c = 0; c < 2; c++)
            aQ[m][c] = *(const bf16x8*)(Qrow + (long)(m * 16) * 1024 + c * 32 + quad * 8);

    const short* Ktb = Kt2 + (long)bh * (SEQ * 64) + (long)ksel * 16 * 4096;
    const short* Vtb = Vt2 + (long)bh * (SEQ * 64) + (long)ksel * 16 * 4096;

    f32x4 O[2][4] = {};
    f32x4 Lacc[2] = {};
    bf16x8 ones;
    #pragma unroll
    for (int i = 0; i < 8; i++) ones[i] = (short)0x3F80;   // bf16 1.0

    for (int t = 0; t < 16; t++) {
        const short* Kt = Ktb + t * 4096;
        const short* Vt = Vtb + t * 4096;

        // K fragment loads (coalesced 1KB dwordx4)
        bf16x8 kf[8];
        #pragma unroll
        for (int u = 0; u < 8; u++) kf[u] = *(const bf16x8*)(Kt + u * 512 + lane * 8);

        // S = Q K^T: 2 m-frags x 4 key-cols, 2 chained d-chunks each
        f32x4 z[2][4];
        #pragma unroll
        for (int m = 0; m < 2; m++)
            #pragma unroll
            for (int kc = 0; kc < 4; kc++) {
                f32x4 zz = {};
                zz = __builtin_amdgcn_mfma_f32_16x16x32_bf16(aQ[m][0], kf[2 * kc],     zz, 0, 0, 0);
                z[m][kc] = __builtin_amdgcn_mfma_f32_16x16x32_bf16(aQ[m][1], kf[2 * kc + 1], zz, 0, 0, 0);
            }

        // V fragment loads — issued now, consumed after exp/pack (latency hidden)
        bf16x8 vf[8];
        #pragma unroll
        for (int u = 0; u < 8; u++) vf[u] = *(const bf16x8*)(Vt + u * 512 + lane * 8);

        // p = exp2(z) (raw v_exp_f32); packed bf16 cvt; one b64 write per (m,r)
        #pragma unroll
        for (int m = 0; m < 2; m++)
            #pragma unroll
            for (int r = 0; r < 4; r++) {
                unsigned d0 = pk_bf16(EXP2F(z[m][0][r]), EXP2F(z[m][1][r]));
                unsigned d1 = pk_bf16(EXP2F(z[m][2][r]), EXP2F(z[m][3][r]));
                unsigned long long dd = ((unsigned long long)d1 << 32) | d0;
                *(unsigned long long*)((unsigned*)PsW + (m * 16 + quad * 4 + r) * 36 + 2 * l16) = dd;
            }

        // PV + row-sum (ones-column MFMA); bV shared across both m-frags
        #pragma unroll
        for (int c = 0; c < 2; c++) {
            bf16x8 aP0 = *(const bf16x8*)(PsW + (l16) * 72      + c * 32 + quad * 8);
            bf16x8 aP1 = *(const bf16x8*)(PsW + (16 + l16) * 72 + c * 32 + quad * 8);
            Lacc[0] = __builtin_amdgcn_mfma_f32_16x16x32_bf16(aP0, ones, Lacc[0], 0, 0, 0);
            Lacc[1] = __builtin_amdgcn_mfma_f32_16x16x32_bf16(aP1, ones, Lacc[1], 0, 0, 0);
            #pragma unroll
            for (int j = 0; j < 4; j++) {
                O[0][j] = __builtin_amdgcn_mfma_f32_16x16x32_bf16(aP0, vf[c * 4 + j], O[0][j], 0, 0, 0);
                O[1][j] = __builtin_amdgcn_mfma_f32_16x16x32_bf16(aP1, vf[c * 4 + j], O[1][j], 0, 0, 0);
            }
        }
    }

    // additive merge of key-split partners (w, w+2) — Ps is dead, reuse as Mg
    __syncthreads();
    if (ksel) {
        float* mg = &sh.Mg[qsel][lane][0];
        #pragma unroll
        for (int m = 0; m < 2; m++)
            #pragma unroll
            for (int j = 0; j < 4; j++)
                #pragma unroll
                for (int r = 0; r < 4; r++)
                    mg[m * 16 + j * 4 + r] = O[m][j][r];
        #pragma unroll
        for (int m = 0; m < 2; m++)
            #pragma unroll
            for (int r = 0; r < 4; r++)
                mg[32 + m * 4 + r] = Lacc[m][r];
    }
    __syncthreads();
    if (!ksel) {
        const float* mg = &sh.Mg[qsel][lane][0];
        #pragma unroll
        for (int m = 0; m < 2; m++)
            #pragma unroll
            for (int j = 0; j < 4; j++)
                #pragma unroll
                for (int r = 0; r < 4; r++)
                    O[m][j][r] += mg[m * 16 + j * 4 + r];
        #pragma unroll
        for (int m = 0; m < 2; m++)
            #pragma unroll
            for (int r = 0; r < 4; r++)
                Lacc[m][r] += mg[32 + m * 4 + r];

        #pragma unroll
        for (int m = 0; m < 2; m++) {
            f32x4 rl;
            #pragma unroll
            for (int r = 0; r < 4; r++) rl[r] = 1.0f / Lacc[m][r];
            #pragma unroll
            for (int j = 0; j < 4; j++)
                #pragma unroll
                for (int r = 0; r < 4; r++) {
                    int row = qw + m * 16 + quad * 4 + r;
                    y[((long)b * SEQ + row) * D_MODEL + h * HD + j * 16 + l16] =
                        f2bf(O[m][j][r] * rl[r]);
                }
        }
    }
}

// ---------------------------------------------------------------------------
// Workspace (48 MB): Qb@0, Kb-slot@8M (used only as yb), Vb-slot@16M (free),
// Kt2@24M, Vt2@32M, WqkvT@40M, WoT@46M. x_bf scratched in d_out.
// repack_kv is GONE — gemm_qkv writes Kt2/Vt2 directly.
// ---------------------------------------------------------------------------
extern "C" void kernel_launch(void* const* d_in, const int* in_sizes, int n_in,
                              void* d_out, int out_size, void* d_ws, size_t ws_size,
                              hipStream_t stream) {
    const float* x    = (const float*)d_in[0];
    const float* Wqkv = (const float*)d_in[1];
    const float* Wo   = (const float*)d_in[2];

    char* ws = (char*)d_ws;
    short* Qb    = (short*)(ws);
    short* Kt2   = (short*)(ws + 25165824);
    short* Vt2   = (short*)(ws + 33554432);
    short* WqkvT = (short*)(ws + 41943040);
    short* WoT   = (short*)(ws + 48234496);
    short* x_bf  = (short*)d_out;            // scratch in d_out (16 MB fp32)
    short* yb    = (short*)(ws + 8388608);   // old Kb slot, free workspace

    const float cexp = 0.125f * 1.4426950408889634f;  // 1/sqrt(64) * log2(e)

    prep_kernel<<<8192, 256, 0, stream>>>(x, x_bf, Wqkv, WqkvT, Wo, WoT, cexp);

    gemm_qkv<<<dim3(3 * D_MODEL / 128, NTOK / 128), 256, 0, stream>>>(
        x_bf, WqkvT, Qb, Kt2, Vt2);

    flash_attn<<<dim3(SEQ / 64, BATCH * NHEADS), 256, 0, stream>>>(Qb, Kt2, Vt2, yb);

    gemm_out<<<dim3(D_MODEL / 64, NTOK / 128), 256, 0, stream>>>(
        yb, WoT, (float*)d_out, NTOK, D_MODEL, D_MODEL);
}